// Round 9
// baseline (89.837 us; speedup 1.0000x reference)
//
#include <hip/hip_runtime.h>
#include <hip/hip_bf16.h>

typedef __attribute__((ext_vector_type(8))) __bf16 bf16x8;
typedef __attribute__((ext_vector_type(4))) float f32x4;

#if __has_builtin(__builtin_amdgcn_sad_u8)
__device__ __forceinline__ unsigned sad8(unsigned a, unsigned b, unsigned acc) {
    return __builtin_amdgcn_sad_u8(a, b, acc);
}
#else
__device__ __forceinline__ unsigned sad8(unsigned a, unsigned b, unsigned acc) {
    #pragma unroll
    for (int i = 0; i < 4; ++i) {
        int xa = (a >> (8 * i)) & 255, xb = (b >> (8 * i)) & 255;
        acc += (unsigned)((xa > xb) ? (xa - xb) : (xb - xa));
    }
    return acc;
}
#endif

// ---------------------------------------------------------------------------
// prep (fallback path only): W1 [128 k][128 col] f32 -> W1t [col][k] bf16
// ---------------------------------------------------------------------------
__global__ void prep_w1_kernel(const float* __restrict__ W1,
                               __bf16* __restrict__ W1t) {
    int i = blockIdx.x * 256 + threadIdx.x;
    int c = i >> 7;
    int k = i & 127;
    W1t[i] = (__bf16)W1[k * 128 + c];
}

// ---------------------------------------------------------------------------
// prep A: sign-sort permutation + quant scale (+ zero the dst-pattern flag).
// ---------------------------------------------------------------------------
__global__ void prep_sign_kernel(const float* __restrict__ W2,
                                 int* __restrict__ perm_inv,
                                 int* __restrict__ npout,
                                 float* __restrict__ qs,
                                 int* __restrict__ flag) {
    __shared__ int wcnt[2];
    __shared__ float wmax[2];
    const int c = threadIdx.x;        // 0..127
    const int lane = c & 63, w = c >> 6;
    const float w2 = W2[c];
    const bool pos = (w2 > 0.f);
    unsigned long long b = __ballot(pos);
    int rank = __popcll(b & ((1ull << lane) - 1ull));
    int cnt  = __popcll(b);
    float m = __builtin_fabsf(w2);
    #pragma unroll
    for (int d = 1; d < 64; d <<= 1) m = fmaxf(m, __shfl_xor(m, d, 64));
    if (lane == 0) { wcnt[w] = cnt; wmax[w] = m; }
    __syncthreads();
    const int np    = wcnt[0] + wcnt[1];
    const int basep = (w == 1) ? wcnt[0] : 0;
    const int negb  = (w == 1) ? (64 - wcnt[0]) : 0;
    const int p = pos ? (basep + rank) : (np + negb + (lane - rank));
    perm_inv[p] = c;
    if (c == 0) {
        float mm = fmaxf(wmax[0], wmax[1]);
        float s  = (mm > 0.f) ? (6.0f * mm / 120.0f) : 1.0f;
        qs[0] = 1.0f / s;
        qs[1] = 0.495f * s;
        *npout = np;
        *flag  = 0;
    }
}

// ---------------------------------------------------------------------------
// verify: flag=1 unless dst[e] == e>>4 for all e (canonical repeat pattern).
// ---------------------------------------------------------------------------
__global__ void verify_dst_kernel(const int* __restrict__ dst, int E,
                                  int* __restrict__ flag) {
    const int t = blockIdx.x * 256 + threadIdx.x;
    const int i = t * 4;
    if (i + 3 >= E) {
        for (int j = i; j < E; ++j)
            if (dst[j] != (j >> 4)) *flag = 1;
        return;
    }
    int4 v = *(const int4*)(dst + i);
    bool bad = (v.x != (i >> 4)) | (v.y != ((i + 1) >> 4)) |
               (v.z != ((i + 2) >> 4)) | (v.w != ((i + 3) >> 4));
    if (bad) *flag = 1;
}

// ---------------------------------------------------------------------------
// prep B: permuted weights. MFMA column j = ct*16+cc maps to table rank
// p = cc*8+ct; source H-column c = perm_inv[p].
// ---------------------------------------------------------------------------
__global__ void prep_w1p_kernel(const float* __restrict__ W1,
                                const float* __restrict__ b1,
                                const float* __restrict__ W2,
                                const int* __restrict__ perm_inv,
                                __bf16* __restrict__ W1pt,
                                float* __restrict__ b1p,
                                float* __restrict__ w2p) {
    int i = blockIdx.x * 256 + threadIdx.x;
    int j = i >> 7;
    int k = i & 127;
    int c = perm_inv[(j & 15) * 8 + (j >> 4)];
    W1pt[i] = (__bf16)W1[k * 128 + c];
    if (k == 0) { b1p[j] = b1[c]; w2p[j] = W2[c]; }
}

// ---------------------------------------------------------------------------
// Fused precompute (one wave per 16-node tile, both halves) + filler writes.
//   rawA = nf@W1[0:64]+b1 -> A1u u8 (128 B/row), R1 = 0.505*rs + b2
//   rawB = nf@W1[64:128]  -> A2q u4 (64 B/row, interleaved nibbles), R2
// Also fills out[n][16..31] = -1e10 (or [0..31] if flag: edge overwrites).
// ---------------------------------------------------------------------------
__global__ void precomp_kernel(const float* __restrict__ nf,
                               const float* __restrict__ b1p,
                               const float* __restrict__ w2p,
                               const float* __restrict__ b2,
                               const __bf16* __restrict__ W1pt,
                               const float* __restrict__ qs,
                               const int* __restrict__ flagp,
                               unsigned char* __restrict__ A1u,
                               unsigned char* __restrict__ A2q,
                               float* __restrict__ R1,
                               float* __restrict__ R2,
                               float* __restrict__ out,
                               int T2, int K) {
    const int lane = threadIdx.x & 63;
    const int wid  = threadIdx.x >> 6;
    const int cc   = lane & 15;
    const int kg   = lane >> 4;
    const int g    = blockIdx.x * 4 + wid;
    if (g >= T2) return;
    const float inv_s = qs[0];

    const float* ap = nf + ((long)g * 16 + cc) * 64 + kg * 8;
    f32x4 lo0 = *(const f32x4*)(ap);
    f32x4 hi0 = *(const f32x4*)(ap + 4);
    f32x4 lo1 = *(const f32x4*)(ap + 32);
    f32x4 hi1 = *(const f32x4*)(ap + 36);
    bf16x8 a0, a1;
    #pragma unroll
    for (int j = 0; j < 4; ++j) {
        a0[j] = (__bf16)lo0[j]; a0[4 + j] = (__bf16)hi0[j];
        a1[j] = (__bf16)lo1[j]; a1[4 + j] = (__bf16)hi1[j];
    }

    float bw[8], wv[8], m8[8];
    #pragma unroll
    for (int ct = 0; ct < 8; ++ct) {
        const int col = ct * 16 + cc;
        const float w2v = w2p[col];
        bw[ct] = b1p[col];
        wv[ct] = w2v;
        m8[ct] = inv_s * __builtin_fabsf(w2v);
    }
    const float b2v = b2[0];

    f32x4 accB[8];
    #pragma unroll
    for (int ct = 0; ct < 8; ++ct) {
        const __bf16* colp = W1pt + (ct * 16 + cc) * 128 + 64 + kg * 8;
        bf16x8 bf0 = *(const bf16x8*)(colp);
        bf16x8 bf1 = *(const bf16x8*)(colp + 32);
        f32x4 acc = (f32x4){0.f, 0.f, 0.f, 0.f};
        acc = __builtin_amdgcn_mfma_f32_16x16x32_bf16(a0, bf0, acc, 0, 0, 0);
        acc = __builtin_amdgcn_mfma_f32_16x16x32_bf16(a1, bf1, acc, 0, 0, 0);
        accB[ct] = acc;
    }
    f32x4 accA[8];
    #pragma unroll
    for (int ct = 0; ct < 8; ++ct) {
        const __bf16* colp = W1pt + (ct * 16 + cc) * 128 + kg * 8;
        bf16x8 bf0 = *(const bf16x8*)(colp);
        bf16x8 bf1 = *(const bf16x8*)(colp + 32);
        f32x4 acc = (f32x4){0.f, 0.f, 0.f, 0.f};
        acc = __builtin_amdgcn_mfma_f32_16x16x32_bf16(a0, bf0, acc, 0, 0, 0);
        acc = __builtin_amdgcn_mfma_f32_16x16x32_bf16(a1, bf1, acc, 0, 0, 0);
        accA[ct] = acc;
    }

    #pragma unroll
    for (int r = 0; r < 4; ++r) {
        const long n = (long)g * 16 + kg * 4 + r;
        float rs1 = 0.f, rs2 = 0.f;
        unsigned u8v[8];
        unsigned pk = 0;
        #pragma unroll
        for (int ct = 0; ct < 8; ++ct) {
            const float rawA = accA[ct][r] + bw[ct];
            const float rawB = accB[ct][r];
            rs1 = fmaf(rawA, wv[ct], rs1);
            rs2 = fmaf(rawB, wv[ct], rs2);
            float xA = fmaf(rawA, m8[ct], 128.f);
            xA = fminf(fmaxf(xA, 1.f), 254.f);
            u8v[ct] = (unsigned)(xA + 0.5f);
            float xB = fmaf(rawB, -0.0625f * m8[ct], 8.f);
            xB = fminf(fmaxf(xB, 1.f), 15.f);
            const unsigned w4 = (unsigned)(xB + 0.5f);
            const int nib = (ct < 4) ? (2 * ct) : (2 * (ct - 4) + 1);
            pk |= w4 << (4 * nib);
        }
        rs1 += __shfl_xor(rs1, 1, 64);
        rs1 += __shfl_xor(rs1, 2, 64);
        rs1 += __shfl_xor(rs1, 4, 64);
        rs1 += __shfl_xor(rs1, 8, 64);
        rs2 += __shfl_xor(rs2, 1, 64);
        rs2 += __shfl_xor(rs2, 2, 64);
        rs2 += __shfl_xor(rs2, 4, 64);
        rs2 += __shfl_xor(rs2, 8, 64);

        int2 o;
        o.x = (int)(u8v[0] | (u8v[1] << 8) | (u8v[2] << 16) | (u8v[3] << 24));
        o.y = (int)(u8v[4] | (u8v[5] << 8) | (u8v[6] << 16) | (u8v[7] << 24));
        *(int2*)(A1u + n * 128 + cc * 8) = o;
        *(unsigned*)(A2q + n * 64 + cc * 4) = pk;
        if (cc == 0) {
            R1[n] = 0.505f * rs1 + b2v;
            R2[n] = 0.505f * rs2;
        }
    }

    // filler slots for the 16 nodes of this tile (1 f32x4 per lane)
    const int flag = *flagp;
    const long node = (long)g * 16 + (lane >> 2);
    const f32x4 fill = (f32x4){-1e10f, -1e10f, -1e10f, -1e10f};
    *(f32x4*)(out + node * K + 16 + (lane & 3) * 4) = fill;
    if (flag)
        *(f32x4*)(out + node * K + (lane & 3) * 4) = fill;
}

// ---------------------------------------------------------------------------
// Edge pass: 4 consecutive 64-edge batches per wave, software-pipelined.
// Fast path (flag==0): dv = e>>4, slot = e&15 -> A1/R1 addresses independent
// of any load. Only the src -> A2/R2 chain has gather latency; 4 independent
// chains per wave. One 4-B score store per edge (fillers done in precomp).
//   score = R1[dv] + R2[se] + 0.495*s*(2*S_plus - S_all)
// ---------------------------------------------------------------------------
__global__ void edge_kernel(const unsigned char* __restrict__ A1u,
                            const unsigned char* __restrict__ A2q,
                            const float* __restrict__ R1,
                            const float* __restrict__ R2,
                            const float* __restrict__ qs,
                            const int* __restrict__ npp,
                            const int* __restrict__ flagp,
                            const int* __restrict__ src,
                            const int* __restrict__ dst,
                            float* __restrict__ out,
                            int E, int K) {
    const int lane = threadIdx.x & 63;
    const int gw   = blockIdx.x * 4 + (threadIdx.x >> 6);
    const float k0 = qs[1];
    const int np   = *npp;
    const int flag = *flagp;

    unsigned mA[16], mB[16];          // wave-uniform -> SGPR
    #pragma unroll
    for (int d = 0; d < 16; ++d) {
        const int ra = np - 8 * d;
        const int rb = ra - 4;
        mA[d] = (ra >= 4) ? 0xFFFFFFFFu
              : ((ra <= 0) ? 0u : (0xFFFFFFFFu >> (8 * (4 - ra))));
        mB[d] = (rb >= 4) ? 0xFFFFFFFFu
              : ((rb <= 0) ? 0u : (0xFFFFFFFFu >> (8 * (4 - rb))));
    }

    const long base = (long)gw * 256;
    if (base >= E) return;
    const bool v1 = base + 128 <= E;
    const bool v2 = base + 192 <= E;
    const bool v3 = base + 256 <= E;
    const int e0 = (int)base + lane;

    const int s0 = src[e0];
    const int s1 = v1 ? src[e0 + 64]  : s0;
    const int s2 = v2 ? src[e0 + 128] : s0;
    const int s3 = v3 ? src[e0 + 192] : s0;

    auto compute = [&](int ee, const int4 (&b)[4], float r2v, bool valid) {
        int dv, slot;
        if (!flag) { dv = ee >> 4; slot = ee & 15; }
        else {
            dv = dst[ee];
            int lo = 0, hi = ee;
            while (lo < hi) {
                int mid = (lo + hi) >> 1;
                if (dst[mid] < dv) lo = mid + 1; else hi = mid;
            }
            slot = ee - lo;
        }
        const unsigned char* ap_ = A1u + (long)dv * 128;
        int4 a[8];
        #pragma unroll
        for (int i = 0; i < 8; ++i) a[i] = *(const int4*)(ap_ + i * 16);
        const float r12 = R1[dv] + r2v;

        unsigned sall = 0, spl = 0;
#define PROC(vv, alo, ahi, d)                                                \
        {                                                                    \
            const unsigned yA = ((unsigned)(vv) << 4) & 0xF0F0F0F0u;         \
            const unsigned yB = (unsigned)(vv) & 0xF0F0F0F0u;                \
            sall = sad8((unsigned)(alo), yA, sall);                          \
            sall = sad8((unsigned)(ahi), yB, sall);                          \
            spl  = sad8((unsigned)(alo) & mA[d], yA & mA[d], spl);           \
            spl  = sad8((unsigned)(ahi) & mB[d], yB & mB[d], spl);           \
        }
        #pragma unroll
        for (int i = 0; i < 4; ++i) {
            const int4 bb  = b[i];
            const int4 alo = a[2 * i];
            const int4 ahi = a[2 * i + 1];
            PROC(bb.x, alo.x, alo.y, 4 * i + 0)
            PROC(bb.y, alo.z, alo.w, 4 * i + 1)
            PROC(bb.z, ahi.x, ahi.y, 4 * i + 2)
            PROC(bb.w, ahi.z, ahi.w, 4 * i + 3)
        }
#undef PROC
        const float score = fmaf(k0, 2.0f * (float)spl - (float)sall, r12);
        if (valid && slot < K)
            out[(long)dv * K + slot] = score;
    };

#define LOADB(bi, r2x, s)                                                    \
    {                                                                        \
        const unsigned char* bp = A2q + (long)(s) * 64;                      \
        bi[0] = *(const int4*)(bp);                                          \
        bi[1] = *(const int4*)(bp + 16);                                     \
        bi[2] = *(const int4*)(bp + 32);                                     \
        bi[3] = *(const int4*)(bp + 48);                                     \
        r2x = R2[s];                                                         \
    }
    int4 b0[4], b1[4], b2[4], b3[4];
    float r2_0, r2_1, r2_2, r2_3;
    LOADB(b0, r2_0, s0)
    LOADB(b1, r2_1, s1)
    compute(e0, b0, r2_0, true);
    LOADB(b2, r2_2, s2)
    compute(e0 + 64, b1, r2_1, v1);
    LOADB(b3, r2_3, s3)
    compute(e0 + 128, b2, r2_2, v2);
    compute(e0 + 192, b3, r2_3, v3);
#undef LOADB
}

// ---------------------------------------------------------------------------
// Fallback (round-1 kernel) for non-special shapes / tiny ws.
// ---------------------------------------------------------------------------
__global__ void attack_kernel_f(
    const float* __restrict__ nf, const float* __restrict__ b1,
    const float* __restrict__ W2, const float* __restrict__ b2,
    const int* __restrict__ src, const int* __restrict__ dst,
    const __bf16* __restrict__ W1t, float* __restrict__ out,
    int T, int K, int DEG)
{
    const int lane = threadIdx.x & 63;
    const int wid  = threadIdx.x >> 6;
    const int row  = lane & 15;
    const int kg   = lane >> 4;

    bf16x8 bfrag[8][4];
    #pragma unroll
    for (int ct = 0; ct < 8; ++ct) {
        const __bf16* colp = W1t + (ct * 16 + row) * 128 + kg * 8;
        #pragma unroll
        for (int kk = 0; kk < 4; ++kk)
            bfrag[ct][kk] = *(const bf16x8*)(colp + kk * 32);
    }
    float b1c[8], w2c[8];
    #pragma unroll
    for (int ct = 0; ct < 8; ++ct) {
        b1c[ct] = b1[ct * 16 + row];
        w2c[ct] = W2[ct * 16 + row];
    }
    const float b2v = b2[0];

    const int wstride = gridDim.x * 4;
    for (int t = blockIdx.x * 4 + wid; t < T; t += wstride) {
        const long eb = (long)t * DEG;
        const int dv = dst[eb];
        const int sv = src[eb + row];
        bf16x8 afrag[4];
        const float* dp = nf + (long)dv * 64 + kg * 8;
        const float* sp = nf + (long)sv * 64 + kg * 8;
        #pragma unroll
        for (int kk = 0; kk < 2; ++kk) {
            f32x4 lo = *(const f32x4*)(dp + kk * 32);
            f32x4 hi = *(const f32x4*)(dp + kk * 32 + 4);
            bf16x8 a;
            #pragma unroll
            for (int j = 0; j < 4; ++j) { a[j] = (__bf16)lo[j]; a[4 + j] = (__bf16)hi[j]; }
            afrag[kk] = a;
        }
        #pragma unroll
        for (int kk = 0; kk < 2; ++kk) {
            f32x4 lo = *(const f32x4*)(sp + kk * 32);
            f32x4 hi = *(const f32x4*)(sp + kk * 32 + 4);
            bf16x8 a;
            #pragma unroll
            for (int j = 0; j < 4; ++j) { a[j] = (__bf16)lo[j]; a[4 + j] = (__bf16)hi[j]; }
            afrag[2 + kk] = a;
        }
        f32x4 acc[8];
        #pragma unroll
        for (int ct = 0; ct < 8; ++ct) acc[ct] = (f32x4){0.f, 0.f, 0.f, 0.f};
        #pragma unroll
        for (int ct = 0; ct < 8; ++ct) {
            #pragma unroll
            for (int kk = 0; kk < 4; ++kk)
                acc[ct] = __builtin_amdgcn_mfma_f32_16x16x32_bf16(
                    afrag[kk], bfrag[ct][kk], acc[ct], 0, 0, 0);
        }
        float part[4] = {0.f, 0.f, 0.f, 0.f};
        #pragma unroll
        for (int ct = 0; ct < 8; ++ct) {
            #pragma unroll
            for (int r = 0; r < 4; ++r) {
                float h = acc[ct][r] + b1c[ct];
                h = fmaxf(h, 0.01f * h);
                part[r] = fmaf(h, w2c[ct], part[r]);
            }
        }
        #pragma unroll
        for (int m = 1; m < 16; m <<= 1) {
            #pragma unroll
            for (int r = 0; r < 4; ++r)
                part[r] += __shfl_xor(part[r], m, 64);
        }
        float* orow = out + (long)dv * K;
        if (row == 0) {
            f32x4 v;
            #pragma unroll
            for (int r = 0; r < 4; ++r) v[r] = part[r] + b2v;
            *(f32x4*)(orow + kg * 4) = v;
            *(f32x4*)(orow + DEG + kg * 4) = (f32x4){-1e10f, -1e10f, -1e10f, -1e10f};
        }
    }
}

extern "C" void kernel_launch(void* const* d_in, const int* in_sizes, int n_in,
                              void* d_out, int out_size, void* d_ws, size_t ws_size,
                              hipStream_t stream) {
    const float* nf  = (const float*)d_in[0];
    const float* W1  = (const float*)d_in[1];
    const float* b1  = (const float*)d_in[2];
    const float* W2  = (const float*)d_in[3];
    const float* b2  = (const float*)d_in[4];
    const int*   src = (const int*)d_in[5];
    const int*   dst = (const int*)d_in[6];
    float* out = (float*)d_out;

    const int H    = in_sizes[2];          // 128
    const int twoD = in_sizes[1] / H;      // 128
    const int D    = twoD / 2;             // 64
    const int N    = in_sizes[0] / D;      // 100000
    const int E    = in_sizes[5];          // 1600000
    const int DEG  = E / N;                // 16
    const int K    = out_size / N;         // 32

    // ws layout
    const size_t w1_off   = 0;                 // 32 KiB (W1pt or W1t)
    const size_t qs_off   = 32768;             // 16 B
    const size_t np_off   = 32784;             // 4 B
    const size_t flag_off = 32788;             // 4 B
    const size_t pinv_off = 32800;             // 512 B
    const size_t b1p_off  = 33312;             // 512 B
    const size_t w2p_off  = 33824;             // 512 B
    const size_t A1_off   = 34560;             // 256-aligned
    const size_t A1_sz    = (size_t)N * 128;   // u8 table
    const size_t A2_off   = A1_off + A1_sz;
    const size_t A2_sz    = (size_t)N * 64;    // u4 table
    const size_t R1_off   = A2_off + A2_sz;
    const size_t R2_off   = R1_off + (size_t)N * sizeof(float);
    const size_t need     = R2_off + (size_t)N * sizeof(float);

    const bool special = (D == 64 && H == 128 && DEG == 16 && K == 32 &&
                          (N % 16) == 0 && (E % 64) == 0 && ws_size >= need);
    if (special) {
        __bf16*        W1pt = (__bf16*)((char*)d_ws + w1_off);
        float*         qs   = (float*)((char*)d_ws + qs_off);
        int*           npp  = (int*)((char*)d_ws + np_off);
        int*           flg  = (int*)((char*)d_ws + flag_off);
        int*           pinv = (int*)((char*)d_ws + pinv_off);
        float*         b1p  = (float*)((char*)d_ws + b1p_off);
        float*         w2p  = (float*)((char*)d_ws + w2p_off);
        unsigned char* A1u  = (unsigned char*)d_ws + A1_off;
        unsigned char* A2q  = (unsigned char*)d_ws + A2_off;
        float*         R1   = (float*)((char*)d_ws + R1_off);
        float*         R2   = (float*)((char*)d_ws + R2_off);

        prep_sign_kernel<<<1, 128, 0, stream>>>(W2, pinv, npp, qs, flg);
        verify_dst_kernel<<<(E / 4 + 255) / 256, 256, 0, stream>>>(dst, E, flg);
        prep_w1p_kernel<<<64, 256, 0, stream>>>(W1, b1, W2, pinv, W1pt, b1p, w2p);
        const int T2 = N / 16;
        const int pblocks = (T2 + 3) / 4;          // 1 tile per wave
        precomp_kernel<<<pblocks, 256, 0, stream>>>(nf, b1p, w2p, b2, W1pt, qs,
                                                    flg, A1u, A2q, R1, R2,
                                                    out, T2, K);
        const int nwaves  = (E + 255) / 256;       // 256 edges per wave
        const int eblocks = (nwaves + 3) / 4;
        edge_kernel<<<eblocks, 256, 0, stream>>>(A1u, A2q, R1, R2, qs, npp,
                                                 flg, src, dst, out, E, K);
    } else {
        __bf16* W1t = (__bf16*)((char*)d_ws + w1_off);
        prep_w1_kernel<<<(twoD * H + 255) / 256, 256, 0, stream>>>(W1, W1t);
        attack_kernel_f<<<2048, 256, 0, stream>>>(nf, b1, W2, b2, src, dst,
                                                  W1t, out, N, K, DEG);
    }
}

// Round 10
// 72.244 us; speedup vs baseline: 1.2435x; 1.2435x over previous
//
#include <hip/hip_runtime.h>
#include <hip/hip_bf16.h>

typedef __attribute__((ext_vector_type(8))) __bf16 bf16x8;
typedef __attribute__((ext_vector_type(4))) float f32x4;

#if __has_builtin(__builtin_amdgcn_sad_u8)
__device__ __forceinline__ unsigned sad8(unsigned a, unsigned b, unsigned acc) {
    return __builtin_amdgcn_sad_u8(a, b, acc);
}
#else
__device__ __forceinline__ unsigned sad8(unsigned a, unsigned b, unsigned acc) {
    #pragma unroll
    for (int i = 0; i < 4; ++i) {
        int xa = (a >> (8 * i)) & 255, xb = (b >> (8 * i)) & 255;
        acc += (unsigned)((xa > xb) ? (xa - xb) : (xb - xa));
    }
    return acc;
}
#endif

// ---------------------------------------------------------------------------
// prep (fallback path only): W1 [128 k][128 col] f32 -> W1t [col][k] bf16
// ---------------------------------------------------------------------------
__global__ void prep_w1_kernel(const float* __restrict__ W1,
                               __bf16* __restrict__ W1t) {
    int i = blockIdx.x * 256 + threadIdx.x;
    int c = i >> 7;
    int k = i & 127;
    W1t[i] = (__bf16)W1[k * 128 + c];
}

// ---------------------------------------------------------------------------
// Merged prep: every block recomputes the sign-sort permutation locally
// (plus-w2 columns first), then writes its slice of the permuted weights.
// Block 0 thread 0 writes qs/np and zeroes the dst-pattern flag.
// MFMA column j = ct*16+cc <-> rank p = cc*8+ct; H-col c = perm_inv[p].
// ---------------------------------------------------------------------------
__global__ void prep_kernel(const float* __restrict__ W1,
                            const float* __restrict__ b1,
                            const float* __restrict__ W2,
                            __bf16* __restrict__ W1pt,
                            float* __restrict__ b1p,
                            float* __restrict__ w2p,
                            int* __restrict__ npout,
                            float* __restrict__ qs,
                            int* __restrict__ flag) {
    __shared__ int perm_inv_s[128];
    __shared__ int wcnt[2];
    __shared__ float wmax[2];
    const int tid  = threadIdx.x;
    const int lane = tid & 63;
    const int w    = tid >> 6;
    bool pos = false;
    int rank = 0;
    if (tid < 128) {
        const float w2 = W2[tid];
        pos = (w2 > 0.f);
        unsigned long long bal = __ballot(pos);
        rank = __popcll(bal & ((1ull << lane) - 1ull));
        int cnt = __popcll(bal);
        float m = __builtin_fabsf(w2);
        #pragma unroll
        for (int d = 1; d < 64; d <<= 1) m = fmaxf(m, __shfl_xor(m, d, 64));
        if (lane == 0) { wcnt[w] = cnt; wmax[w] = m; }
    }
    __syncthreads();
    if (tid < 128) {
        const int npv   = wcnt[0] + wcnt[1];
        const int basep = (w == 1) ? wcnt[0] : 0;
        const int negb  = (w == 1) ? (64 - wcnt[0]) : 0;
        const int p = pos ? (basep + rank) : (npv + negb + (lane - rank));
        perm_inv_s[p] = tid;
    }
    __syncthreads();

    const int i = blockIdx.x * 256 + tid;     // 64 blocks x 256 = 16384
    const int j = i >> 7;
    const int k = i & 127;
    const int c = perm_inv_s[(j & 15) * 8 + (j >> 4)];
    W1pt[i] = (__bf16)W1[k * 128 + c];
    if (k == 0) { b1p[j] = b1[c]; w2p[j] = W2[c]; }
    if (i == 0) {
        float mm = fmaxf(wmax[0], wmax[1]);
        float s  = (mm > 0.f) ? (6.0f * mm / 120.0f) : 1.0f;
        qs[0] = 1.0f / s;
        qs[1] = 0.495f * s;
        *npout = wcnt[0] + wcnt[1];
        *flag  = 0;
    }
}

// ---------------------------------------------------------------------------
// verify: flag=1 unless dst[e] == e>>4 for all e (canonical repeat pattern).
// ---------------------------------------------------------------------------
__global__ void verify_dst_kernel(const int* __restrict__ dst, int E,
                                  int* __restrict__ flag) {
    const int t = blockIdx.x * 256 + threadIdx.x;
    const int i = t * 4;
    if (i + 3 >= E) {
        for (int j = i; j < E; ++j)
            if (dst[j] != (j >> 4)) *flag = 1;
        return;
    }
    int4 v = *(const int4*)(dst + i);
    bool bad = (v.x != (i >> 4)) | (v.y != ((i + 1) >> 4)) |
               (v.z != ((i + 2) >> 4)) | (v.w != ((i + 3) >> 4));
    if (bad) *flag = 1;
}

// ---------------------------------------------------------------------------
// Fused precompute (one wave per 16-node tile, both MLP halves):
//   rawA = nf@W1[0:64]+b1 -> A1u u8 (128 B/row, TRANSPOSED byte order:
//          byte j holds rank 16*(j>>4) + 4*(j&3) + ((j>>2)&3)), R1
//   rawB = nf@W1[64:128]  -> A2q 2-bit (32 B/row, rank-order fields), R2
// A1 transpose realized with one shfl_xor(1) halfword swap per dword;
// store addresses stay contiguous (int2 @ byte 8*cc). The transposed A1
// order matches plane-extraction ((v>>2k)&0x03030303) of A2 in the edge
// pass, so SAD operands align rank-for-rank.
// If flag set (non-canonical dst): pre-fill all K slots with -1e10.
// ---------------------------------------------------------------------------
__global__ void precomp_kernel(const float* __restrict__ nf,
                               const float* __restrict__ b1p,
                               const float* __restrict__ w2p,
                               const float* __restrict__ b2,
                               const __bf16* __restrict__ W1pt,
                               const float* __restrict__ qs,
                               const int* __restrict__ flagp,
                               unsigned char* __restrict__ A1u,
                               unsigned char* __restrict__ A2q,
                               float* __restrict__ R1,
                               float* __restrict__ R2,
                               float* __restrict__ out,
                               int T2, int K) {
    const int lane = threadIdx.x & 63;
    const int wid  = threadIdx.x >> 6;
    const int cc   = lane & 15;
    const int kg   = lane >> 4;
    const int g    = blockIdx.x * 4 + wid;
    if (g >= T2) return;
    const float inv_s = qs[0];

    const float* ap = nf + ((long)g * 16 + cc) * 64 + kg * 8;
    f32x4 lo0 = *(const f32x4*)(ap);
    f32x4 hi0 = *(const f32x4*)(ap + 4);
    f32x4 lo1 = *(const f32x4*)(ap + 32);
    f32x4 hi1 = *(const f32x4*)(ap + 36);
    bf16x8 a0, a1;
    #pragma unroll
    for (int j = 0; j < 4; ++j) {
        a0[j] = (__bf16)lo0[j]; a0[4 + j] = (__bf16)hi0[j];
        a1[j] = (__bf16)lo1[j]; a1[4 + j] = (__bf16)hi1[j];
    }

    float bw[8], wv[8], m8[8], m85[8];
    #pragma unroll
    for (int ct = 0; ct < 8; ++ct) {
        const int col = ct * 16 + cc;
        const float w2v = w2p[col];
        bw[ct]  = b1p[col];
        wv[ct]  = w2v;
        m8[ct]  = inv_s * __builtin_fabsf(w2v);
        m85[ct] = m8[ct] * (1.0f / 85.0f);
    }
    const float b2v = b2[0];

    f32x4 accB[8];
    #pragma unroll
    for (int ct = 0; ct < 8; ++ct) {
        const __bf16* colp = W1pt + (ct * 16 + cc) * 128 + 64 + kg * 8;
        bf16x8 bf0 = *(const bf16x8*)(colp);
        bf16x8 bf1 = *(const bf16x8*)(colp + 32);
        f32x4 acc = (f32x4){0.f, 0.f, 0.f, 0.f};
        acc = __builtin_amdgcn_mfma_f32_16x16x32_bf16(a0, bf0, acc, 0, 0, 0);
        acc = __builtin_amdgcn_mfma_f32_16x16x32_bf16(a1, bf1, acc, 0, 0, 0);
        accB[ct] = acc;
    }
    f32x4 accA[8];
    #pragma unroll
    for (int ct = 0; ct < 8; ++ct) {
        const __bf16* colp = W1pt + (ct * 16 + cc) * 128 + kg * 8;
        bf16x8 bf0 = *(const bf16x8*)(colp);
        bf16x8 bf1 = *(const bf16x8*)(colp + 32);
        f32x4 acc = (f32x4){0.f, 0.f, 0.f, 0.f};
        acc = __builtin_amdgcn_mfma_f32_16x16x32_bf16(a0, bf0, acc, 0, 0, 0);
        acc = __builtin_amdgcn_mfma_f32_16x16x32_bf16(a1, bf1, acc, 0, 0, 0);
        accA[ct] = acc;
    }

    #pragma unroll
    for (int r = 0; r < 4; ++r) {
        const long n = (long)g * 16 + kg * 4 + r;
        float rs1 = 0.f, rs2 = 0.f;
        unsigned ub[8];
        unsigned pk16 = 0;
        #pragma unroll
        for (int ct = 0; ct < 8; ++ct) {
            const float rawA = accA[ct][r] + bw[ct];
            const float rawB = accB[ct][r];
            rs1 = fmaf(rawA, wv[ct], rs1);
            rs2 = fmaf(rawB, wv[ct], rs2);
            float xA = fmaf(rawA, m8[ct], 128.f);
            xA = fminf(fmaxf(xA, 1.f), 254.f);
            ub[ct] = (unsigned)(xA + 0.5f);
            // 2-bit code: round((128 - rawB*m8)/85) = floor(2.00588 - rawB*m85)
            float tB = fmaf(rawB, -m85[ct], 2.00588f);
            tB = fminf(fmaxf(tB, 0.f), 3.0f);
            pk16 |= ((unsigned)tB) << (2 * ct);
        }
        rs1 += __shfl_xor(rs1, 1, 64);
        rs1 += __shfl_xor(rs1, 2, 64);
        rs1 += __shfl_xor(rs1, 4, 64);
        rs1 += __shfl_xor(rs1, 8, 64);
        rs2 += __shfl_xor(rs2, 1, 64);
        rs2 += __shfl_xor(rs2, 2, 64);
        rs2 += __shfl_xor(rs2, 4, 64);
        rs2 += __shfl_xor(rs2, 8, 64);

        // A1 transposed pack: dword k of 16-byte block (cc>>1) =
        //   even.ub[k] | even.ub[k+4]<<8 | odd.ub[k]<<16 | odd.ub[k+4]<<24
        unsigned half_[4], dw[4];
        #pragma unroll
        for (int k = 0; k < 4; ++k) half_[k] = ub[k] | (ub[k + 4] << 8);
        const bool oddl = (cc & 1);
        #pragma unroll
        for (int k = 0; k < 4; ++k) {
            unsigned ph = (unsigned)__shfl_xor((int)half_[k], 1, 64);
            dw[k] = oddl ? (ph | (half_[k] << 16)) : (half_[k] | (ph << 16));
        }
        int2 st;
        st.x = (int)(oddl ? dw[2] : dw[0]);
        st.y = (int)(oddl ? dw[3] : dw[1]);
        *(int2*)(A1u + n * 128 + cc * 8) = st;
        *(unsigned short*)(A2q + n * 32 + cc * 2) = (unsigned short)pk16;
        if (cc == 0) {
            R1[n] = 0.505f * rs1 + b2v;
            R2[n] = 0.505f * rs2;
        }
    }

    if (*flagp) {   // non-canonical dst: pre-fill all K slots
        const f32x4 fill = (f32x4){-1e10f, -1e10f, -1e10f, -1e10f};
        #pragma unroll
        for (int q = 0; q < 2; ++q) {
            const long node = (long)g * 16 + (lane >> 2);
            *(f32x4*)(out + node * K + (q * 4 + (lane & 3)) * 4) = fill;
        }
    }
}

// ---------------------------------------------------------------------------
// Edge pass, one edge per lane, one-shot wave (round-8 structure):
//   A2 row: 2 int4 (32 B, 3.2 MB table -> per-XCD L2-resident)
//   expand plane k of dword d: x=(v>>2k)&0x03030303, y=x*85 (u8 grid)
//   A1 dword 4d+k matches y's ranks byte-for-byte (transposed pack).
//   score = R1[dv] + R2[se] + 0.495*s*(2*S_plus - S_all)
// ---------------------------------------------------------------------------
__global__ void edge_kernel(const unsigned char* __restrict__ A1u,
                            const unsigned char* __restrict__ A2q,
                            const float* __restrict__ R1,
                            const float* __restrict__ R2,
                            const float* __restrict__ qs,
                            const int* __restrict__ npp,
                            const int* __restrict__ flagp,
                            const int* __restrict__ src,
                            const int* __restrict__ dst,
                            float* __restrict__ out,
                            int E, int K) {
    const int lane = threadIdx.x & 63;
    const int gw   = blockIdx.x * 4 + (threadIdx.x >> 6);
    const float k0 = qs[1];
    const int np   = *npp;
    const int flag = *flagp;

    // mask dword m=4d+k: byte b on iff rank 16d+4b+k < np  (wave-uniform)
    unsigned M[32];
    #pragma unroll
    for (int m = 0; m < 32; ++m) {
        const int d = m >> 2, k = m & 3;
        const int t = np - 16 * d - k;
        int bc = (t <= 0) ? 0 : ((t + 3) >> 2);
        bc = bc > 4 ? 4 : bc;
        M[m] = (bc >= 4) ? 0xFFFFFFFFu
             : ((bc <= 0) ? 0u : (0xFFFFFFFFu >> (8 * (4 - bc))));
    }

    const int e = gw * 64 + lane;
    if (e >= E) return;
    int dv, slot;
    if (!flag) { dv = e >> 4; slot = e & 15; }
    else {
        dv = dst[e];
        int lo = 0, hi = e;
        while (lo < hi) {
            int mid = (lo + hi) >> 1;
            if (dst[mid] < dv) lo = mid + 1; else hi = mid;
        }
        slot = e - lo;
    }
    const int se = src[e];

    const unsigned char* bp = A2q + (long)se * 32;
    int4 q0 = *(const int4*)(bp);
    int4 q1 = *(const int4*)(bp + 16);
    const unsigned char* ap_ = A1u + (long)dv * 128;
    unsigned A[32];
    #pragma unroll
    for (int i = 0; i < 8; ++i) {
        int4 t = *(const int4*)(ap_ + i * 16);
        A[4 * i]     = (unsigned)t.x;
        A[4 * i + 1] = (unsigned)t.y;
        A[4 * i + 2] = (unsigned)t.z;
        A[4 * i + 3] = (unsigned)t.w;
    }
    const float r12 = R1[dv] + R2[se];

    unsigned B[8] = {(unsigned)q0.x, (unsigned)q0.y, (unsigned)q0.z, (unsigned)q0.w,
                     (unsigned)q1.x, (unsigned)q1.y, (unsigned)q1.z, (unsigned)q1.w};
    unsigned sall = 0, spl = 0;
    #pragma unroll
    for (int d = 0; d < 8; ++d) {
        const unsigned v = B[d];
        #pragma unroll
        for (int k = 0; k < 4; ++k) {
            unsigned x = (v >> (2 * k)) & 0x03030303u;
            unsigned y = x + (x << 2);     // x*5
            y = y + (y << 4);              // x*85  (no cross-byte carries)
            const unsigned mm = M[4 * d + k];
            const unsigned aa = A[4 * d + k];
            sall = sad8(aa, y, sall);
            spl  = sad8(aa & mm, y & mm, spl);
        }
    }

    const float score = fmaf(k0, 2.0f * (float)spl - (float)sall, r12);
    if (slot < K) out[(long)dv * K + slot] = score;
    if (!flag) out[(long)dv * K + 16 + slot] = -1e10f;
}

// ---------------------------------------------------------------------------
// Fallback (round-1 kernel) for non-special shapes / tiny ws.
// ---------------------------------------------------------------------------
__global__ void attack_kernel_f(
    const float* __restrict__ nf, const float* __restrict__ b1,
    const float* __restrict__ W2, const float* __restrict__ b2,
    const int* __restrict__ src, const int* __restrict__ dst,
    const __bf16* __restrict__ W1t, float* __restrict__ out,
    int T, int K, int DEG)
{
    const int lane = threadIdx.x & 63;
    const int wid  = threadIdx.x >> 6;
    const int row  = lane & 15;
    const int kg   = lane >> 4;

    bf16x8 bfrag[8][4];
    #pragma unroll
    for (int ct = 0; ct < 8; ++ct) {
        const __bf16* colp = W1t + (ct * 16 + row) * 128 + kg * 8;
        #pragma unroll
        for (int kk = 0; kk < 4; ++kk)
            bfrag[ct][kk] = *(const bf16x8*)(colp + kk * 32);
    }
    float b1c[8], w2c[8];
    #pragma unroll
    for (int ct = 0; ct < 8; ++ct) {
        b1c[ct] = b1[ct * 16 + row];
        w2c[ct] = W2[ct * 16 + row];
    }
    const float b2v = b2[0];

    const int wstride = gridDim.x * 4;
    for (int t = blockIdx.x * 4 + wid; t < T; t += wstride) {
        const long eb = (long)t * DEG;
        const int dv = dst[eb];
        const int sv = src[eb + row];
        bf16x8 afrag[4];
        const float* dp = nf + (long)dv * 64 + kg * 8;
        const float* sp = nf + (long)sv * 64 + kg * 8;
        #pragma unroll
        for (int kk = 0; kk < 2; ++kk) {
            f32x4 lo = *(const f32x4*)(dp + kk * 32);
            f32x4 hi = *(const f32x4*)(dp + kk * 32 + 4);
            bf16x8 a;
            #pragma unroll
            for (int j = 0; j < 4; ++j) { a[j] = (__bf16)lo[j]; a[4 + j] = (__bf16)hi[j]; }
            afrag[kk] = a;
        }
        #pragma unroll
        for (int kk = 0; kk < 2; ++kk) {
            f32x4 lo = *(const f32x4*)(sp + kk * 32);
            f32x4 hi = *(const f32x4*)(sp + kk * 32 + 4);
            bf16x8 a;
            #pragma unroll
            for (int j = 0; j < 4; ++j) { a[j] = (__bf16)lo[j]; a[4 + j] = (__bf16)hi[j]; }
            afrag[2 + kk] = a;
        }
        f32x4 acc[8];
        #pragma unroll
        for (int ct = 0; ct < 8; ++ct) acc[ct] = (f32x4){0.f, 0.f, 0.f, 0.f};
        #pragma unroll
        for (int ct = 0; ct < 8; ++ct) {
            #pragma unroll
            for (int kk = 0; kk < 4; ++kk)
                acc[ct] = __builtin_amdgcn_mfma_f32_16x16x32_bf16(
                    afrag[kk], bfrag[ct][kk], acc[ct], 0, 0, 0);
        }
        float part[4] = {0.f, 0.f, 0.f, 0.f};
        #pragma unroll
        for (int ct = 0; ct < 8; ++ct) {
            #pragma unroll
            for (int r = 0; r < 4; ++r) {
                float h = acc[ct][r] + b1c[ct];
                h = fmaxf(h, 0.01f * h);
                part[r] = fmaf(h, w2c[ct], part[r]);
            }
        }
        #pragma unroll
        for (int m = 1; m < 16; m <<= 1) {
            #pragma unroll
            for (int r = 0; r < 4; ++r)
                part[r] += __shfl_xor(part[r], m, 64);
        }
        float* orow = out + (long)dv * K;
        if (row == 0) {
            f32x4 v;
            #pragma unroll
            for (int r = 0; r < 4; ++r) v[r] = part[r] + b2v;
            *(f32x4*)(orow + kg * 4) = v;
            *(f32x4*)(orow + DEG + kg * 4) = (f32x4){-1e10f, -1e10f, -1e10f, -1e10f};
        }
    }
}

extern "C" void kernel_launch(void* const* d_in, const int* in_sizes, int n_in,
                              void* d_out, int out_size, void* d_ws, size_t ws_size,
                              hipStream_t stream) {
    const float* nf  = (const float*)d_in[0];
    const float* W1  = (const float*)d_in[1];
    const float* b1  = (const float*)d_in[2];
    const float* W2  = (const float*)d_in[3];
    const float* b2  = (const float*)d_in[4];
    const int*   src = (const int*)d_in[5];
    const int*   dst = (const int*)d_in[6];
    float* out = (float*)d_out;

    const int H    = in_sizes[2];          // 128
    const int twoD = in_sizes[1] / H;      // 128
    const int D    = twoD / 2;             // 64
    const int N    = in_sizes[0] / D;      // 100000
    const int E    = in_sizes[5];          // 1600000
    const int DEG  = E / N;                // 16
    const int K    = out_size / N;         // 32

    // ws layout
    const size_t w1_off   = 0;                 // 32 KiB (W1pt or W1t)
    const size_t qs_off   = 32768;             // 16 B
    const size_t np_off   = 32784;             // 4 B
    const size_t flag_off = 32788;             // 4 B
    const size_t b1p_off  = 33312;             // 512 B
    const size_t w2p_off  = 33824;             // 512 B
    const size_t A1_off   = 34560;             // 256-aligned
    const size_t A1_sz    = (size_t)N * 128;   // u8 table (12.8 MB)
    const size_t A2_off   = A1_off + A1_sz;
    const size_t A2_sz    = (size_t)N * 32;    // 2-bit table (3.2 MB)
    const size_t R1_off   = A2_off + A2_sz;
    const size_t R2_off   = R1_off + (size_t)N * sizeof(float);
    const size_t need     = R2_off + (size_t)N * sizeof(float);

    const bool special = (D == 64 && H == 128 && DEG == 16 && K == 32 &&
                          (N % 16) == 0 && (E % 64) == 0 && ws_size >= need);
    if (special) {
        __bf16*        W1pt = (__bf16*)((char*)d_ws + w1_off);
        float*         qs   = (float*)((char*)d_ws + qs_off);
        int*           npp  = (int*)((char*)d_ws + np_off);
        int*           flg  = (int*)((char*)d_ws + flag_off);
        float*         b1p  = (float*)((char*)d_ws + b1p_off);
        float*         w2p  = (float*)((char*)d_ws + w2p_off);
        unsigned char* A1u  = (unsigned char*)d_ws + A1_off;
        unsigned char* A2q  = (unsigned char*)d_ws + A2_off;
        float*         R1   = (float*)((char*)d_ws + R1_off);
        float*         R2   = (float*)((char*)d_ws + R2_off);

        prep_kernel<<<64, 256, 0, stream>>>(W1, b1, W2, W1pt, b1p, w2p,
                                            npp, qs, flg);
        verify_dst_kernel<<<(E / 4 + 255) / 256, 256, 0, stream>>>(dst, E, flg);
        const int T2 = N / 16;
        const int pblocks = (T2 + 3) / 4;          // 1 tile per wave
        precomp_kernel<<<pblocks, 256, 0, stream>>>(nf, b1p, w2p, b2, W1pt, qs,
                                                    flg, A1u, A2q, R1, R2,
                                                    out, T2, K);
        const int eblocks = (E + 255) / 256;       // 64 edges per wave, one-shot
        edge_kernel<<<eblocks, 256, 0, stream>>>(A1u, A2q, R1, R2, qs, npp,
                                                 flg, src, dst, out, E, K);
    } else {
        __bf16* W1t = (__bf16*)((char*)d_ws + w1_off);
        prep_w1_kernel<<<(twoD * H + 255) / 256, 256, 0, stream>>>(W1, W1t);
        attack_kernel_f<<<2048, 256, 0, stream>>>(nf, b1, W2, b2, src, dst,
                                                  W1t, out, N, K, DEG);
    }
}

// Round 11
// 71.668 us; speedup vs baseline: 1.2535x; 1.0080x over previous
//
#include <hip/hip_runtime.h>
#include <hip/hip_bf16.h>

typedef __attribute__((ext_vector_type(8))) __bf16 bf16x8;
typedef __attribute__((ext_vector_type(4))) float f32x4;

#if __has_builtin(__builtin_amdgcn_sad_u8)
__device__ __forceinline__ unsigned sad8(unsigned a, unsigned b, unsigned acc) {
    return __builtin_amdgcn_sad_u8(a, b, acc);
}
#else
__device__ __forceinline__ unsigned sad8(unsigned a, unsigned b, unsigned acc) {
    #pragma unroll
    for (int i = 0; i < 4; ++i) {
        int xa = (a >> (8 * i)) & 255, xb = (b >> (8 * i)) & 255;
        acc += (unsigned)((xa > xb) ? (xa - xb) : (xb - xa));
    }
    return acc;
}
#endif

// ---------------------------------------------------------------------------
// prep (fallback path only): W1 [128 k][128 col] f32 -> W1t [col][k] bf16
// ---------------------------------------------------------------------------
__global__ void prep_w1_kernel(const float* __restrict__ W1,
                               __bf16* __restrict__ W1t) {
    int i = blockIdx.x * 256 + threadIdx.x;
    int c = i >> 7;
    int k = i & 127;
    W1t[i] = (__bf16)W1[k * 128 + c];
}

// ---------------------------------------------------------------------------
// Merged prep: every block recomputes the sign-sort permutation locally
// (plus-w2 columns first), then writes its slice of the permuted weights.
// Block 0 thread 0 writes qs/np and zeroes the dst-pattern flag.
// MFMA column j = ct*16+cc <-> rank p = cc*8+ct; H-col c = perm_inv[p].
// ---------------------------------------------------------------------------
__global__ void prep_kernel(const float* __restrict__ W1,
                            const float* __restrict__ b1,
                            const float* __restrict__ W2,
                            __bf16* __restrict__ W1pt,
                            float* __restrict__ b1p,
                            float* __restrict__ w2p,
                            int* __restrict__ npout,
                            float* __restrict__ qs,
                            int* __restrict__ flag) {
    __shared__ int perm_inv_s[128];
    __shared__ int wcnt[2];
    __shared__ float wmax[2];
    const int tid  = threadIdx.x;
    const int lane = tid & 63;
    const int w    = tid >> 6;
    bool pos = false;
    int rank = 0;
    if (tid < 128) {
        const float w2 = W2[tid];
        pos = (w2 > 0.f);
        unsigned long long bal = __ballot(pos);
        rank = __popcll(bal & ((1ull << lane) - 1ull));
        int cnt = __popcll(bal);
        float m = __builtin_fabsf(w2);
        #pragma unroll
        for (int d = 1; d < 64; d <<= 1) m = fmaxf(m, __shfl_xor(m, d, 64));
        if (lane == 0) { wcnt[w] = cnt; wmax[w] = m; }
    }
    __syncthreads();
    if (tid < 128) {
        const int npv   = wcnt[0] + wcnt[1];
        const int basep = (w == 1) ? wcnt[0] : 0;
        const int negb  = (w == 1) ? (64 - wcnt[0]) : 0;
        const int p = pos ? (basep + rank) : (npv + negb + (lane - rank));
        perm_inv_s[p] = tid;
    }
    __syncthreads();

    const int i = blockIdx.x * 256 + tid;     // 64 blocks x 256 = 16384
    const int j = i >> 7;
    const int k = i & 127;
    const int c = perm_inv_s[(j & 15) * 8 + (j >> 4)];
    W1pt[i] = (__bf16)W1[k * 128 + c];
    if (k == 0) { b1p[j] = b1[c]; w2p[j] = W2[c]; }
    if (i == 0) {
        float mm = fmaxf(wmax[0], wmax[1]);
        float s  = (mm > 0.f) ? (6.0f * mm / 120.0f) : 1.0f;
        qs[0] = 1.0f / s;
        qs[1] = 0.495f * s;
        *npout = wcnt[0] + wcnt[1];
        *flag  = 0;
    }
}

// ---------------------------------------------------------------------------
// verify: flag=1 unless dst[e] == e>>4 for all e (canonical repeat pattern).
// ---------------------------------------------------------------------------
__global__ void verify_dst_kernel(const int* __restrict__ dst, int E,
                                  int* __restrict__ flag) {
    const int t = blockIdx.x * 256 + threadIdx.x;
    const int i = t * 4;
    if (i + 3 >= E) {
        for (int j = i; j < E; ++j)
            if (dst[j] != (j >> 4)) *flag = 1;
        return;
    }
    int4 v = *(const int4*)(dst + i);
    bool bad = (v.x != (i >> 4)) | (v.y != ((i + 1) >> 4)) |
               (v.z != ((i + 2) >> 4)) | (v.w != ((i + 3) >> 4));
    if (bad) *flag = 1;
}

// ---------------------------------------------------------------------------
// Fused precompute (one wave per 16-node tile, both MLP halves):
//   rawA = nf@W1[0:64]+b1 -> A1u u8 (128 B/row, TRANSPOSED byte order:
//          byte j holds rank 16*(j>>4) + 4*(j&3) + ((j>>2)&3)), R1
//   rawB = nf@W1[64:128]  -> A2q 2-bit (32 B/row, rank-order fields), R2
// A1 transpose realized with one shfl_xor(1) halfword swap per dword;
// store addresses stay contiguous (int2 @ byte 8*cc). The transposed A1
// order matches plane-extraction ((v>>2k)&0x03030303) of A2 in the edge
// pass, so SAD operands align rank-for-rank.
// If flag set (non-canonical dst): pre-fill all K slots with -1e10.
// __launch_bounds__(256,2): VGPR cap 256 — live state is ~160 regs
// (accA[8]+accB[8]=64 f32x4 alone); the compiler's default 64-VGPR tier
// spilled to scratch (r10: 45us, VALUBusy 12%). 2 waves/EU is plenty.
// ---------------------------------------------------------------------------
__global__ __launch_bounds__(256, 2) void precomp_kernel(
                               const float* __restrict__ nf,
                               const float* __restrict__ b1p,
                               const float* __restrict__ w2p,
                               const float* __restrict__ b2,
                               const __bf16* __restrict__ W1pt,
                               const float* __restrict__ qs,
                               const int* __restrict__ flagp,
                               unsigned char* __restrict__ A1u,
                               unsigned char* __restrict__ A2q,
                               float* __restrict__ R1,
                               float* __restrict__ R2,
                               float* __restrict__ out,
                               int T2, int K) {
    const int lane = threadIdx.x & 63;
    const int wid  = threadIdx.x >> 6;
    const int cc   = lane & 15;
    const int kg   = lane >> 4;
    const int g    = blockIdx.x * 4 + wid;
    if (g >= T2) return;
    const float inv_s = qs[0];

    const float* ap = nf + ((long)g * 16 + cc) * 64 + kg * 8;
    f32x4 lo0 = *(const f32x4*)(ap);
    f32x4 hi0 = *(const f32x4*)(ap + 4);
    f32x4 lo1 = *(const f32x4*)(ap + 32);
    f32x4 hi1 = *(const f32x4*)(ap + 36);
    bf16x8 a0, a1;
    #pragma unroll
    for (int j = 0; j < 4; ++j) {
        a0[j] = (__bf16)lo0[j]; a0[4 + j] = (__bf16)hi0[j];
        a1[j] = (__bf16)lo1[j]; a1[4 + j] = (__bf16)hi1[j];
    }

    float bw[8], wv[8], m8[8], m85[8];
    #pragma unroll
    for (int ct = 0; ct < 8; ++ct) {
        const int col = ct * 16 + cc;
        const float w2v = w2p[col];
        bw[ct]  = b1p[col];
        wv[ct]  = w2v;
        m8[ct]  = inv_s * __builtin_fabsf(w2v);
        m85[ct] = m8[ct] * (1.0f / 85.0f);
    }
    const float b2v = b2[0];

    f32x4 accB[8];
    #pragma unroll
    for (int ct = 0; ct < 8; ++ct) {
        const __bf16* colp = W1pt + (ct * 16 + cc) * 128 + 64 + kg * 8;
        bf16x8 bf0 = *(const bf16x8*)(colp);
        bf16x8 bf1 = *(const bf16x8*)(colp + 32);
        f32x4 acc = (f32x4){0.f, 0.f, 0.f, 0.f};
        acc = __builtin_amdgcn_mfma_f32_16x16x32_bf16(a0, bf0, acc, 0, 0, 0);
        acc = __builtin_amdgcn_mfma_f32_16x16x32_bf16(a1, bf1, acc, 0, 0, 0);
        accB[ct] = acc;
    }
    f32x4 accA[8];
    #pragma unroll
    for (int ct = 0; ct < 8; ++ct) {
        const __bf16* colp = W1pt + (ct * 16 + cc) * 128 + kg * 8;
        bf16x8 bf0 = *(const bf16x8*)(colp);
        bf16x8 bf1 = *(const bf16x8*)(colp + 32);
        f32x4 acc = (f32x4){0.f, 0.f, 0.f, 0.f};
        acc = __builtin_amdgcn_mfma_f32_16x16x32_bf16(a0, bf0, acc, 0, 0, 0);
        acc = __builtin_amdgcn_mfma_f32_16x16x32_bf16(a1, bf1, acc, 0, 0, 0);
        accA[ct] = acc;
    }

    #pragma unroll
    for (int r = 0; r < 4; ++r) {
        const long n = (long)g * 16 + kg * 4 + r;
        float rs1 = 0.f, rs2 = 0.f;
        unsigned ub[8];
        unsigned pk16 = 0;
        #pragma unroll
        for (int ct = 0; ct < 8; ++ct) {
            const float rawA = accA[ct][r] + bw[ct];
            const float rawB = accB[ct][r];
            rs1 = fmaf(rawA, wv[ct], rs1);
            rs2 = fmaf(rawB, wv[ct], rs2);
            float xA = fmaf(rawA, m8[ct], 128.f);
            xA = fminf(fmaxf(xA, 1.f), 254.f);
            ub[ct] = (unsigned)(xA + 0.5f);
            // 2-bit code: round((128 - rawB*m8)/85) = floor(2.00588 - rawB*m85)
            float tB = fmaf(rawB, -m85[ct], 2.00588f);
            tB = fminf(fmaxf(tB, 0.f), 3.0f);
            pk16 |= ((unsigned)tB) << (2 * ct);
        }
        rs1 += __shfl_xor(rs1, 1, 64);
        rs1 += __shfl_xor(rs1, 2, 64);
        rs1 += __shfl_xor(rs1, 4, 64);
        rs1 += __shfl_xor(rs1, 8, 64);
        rs2 += __shfl_xor(rs2, 1, 64);
        rs2 += __shfl_xor(rs2, 2, 64);
        rs2 += __shfl_xor(rs2, 4, 64);
        rs2 += __shfl_xor(rs2, 8, 64);

        // A1 transposed pack: dword k of 16-byte block (cc>>1) =
        //   even.ub[k] | even.ub[k+4]<<8 | odd.ub[k]<<16 | odd.ub[k+4]<<24
        unsigned half_[4], dw[4];
        #pragma unroll
        for (int k = 0; k < 4; ++k) half_[k] = ub[k] | (ub[k + 4] << 8);
        const bool oddl = (cc & 1);
        #pragma unroll
        for (int k = 0; k < 4; ++k) {
            unsigned ph = (unsigned)__shfl_xor((int)half_[k], 1, 64);
            dw[k] = oddl ? (ph | (half_[k] << 16)) : (half_[k] | (ph << 16));
        }
        int2 st;
        st.x = (int)(oddl ? dw[2] : dw[0]);
        st.y = (int)(oddl ? dw[3] : dw[1]);
        *(int2*)(A1u + n * 128 + cc * 8) = st;
        *(unsigned short*)(A2q + n * 32 + cc * 2) = (unsigned short)pk16;
        if (cc == 0) {
            R1[n] = 0.505f * rs1 + b2v;
            R2[n] = 0.505f * rs2;
        }
    }

    if (*flagp) {   // non-canonical dst: pre-fill all K slots
        const f32x4 fill = (f32x4){-1e10f, -1e10f, -1e10f, -1e10f};
        #pragma unroll
        for (int q = 0; q < 2; ++q) {
            const long node = (long)g * 16 + (lane >> 2);
            *(f32x4*)(out + node * K + (q * 4 + (lane & 3)) * 4) = fill;
        }
    }
}

// ---------------------------------------------------------------------------
// Edge pass, one edge per lane, one-shot wave:
//   A2 row: 2 int4 (32 B, 3.2 MB table -> per-XCD L2-resident)
//   expand plane k of dword d: x=(v>>2k)&0x03030303, y=x*85 (u8 grid)
//   A1 dword 4d+k matches y's ranks byte-for-byte (transposed pack).
//   score = R1[dv] + R2[se] + 0.495*s*(2*S_plus - S_all)
// __launch_bounds__(256,2): A[32]+B[8] + masks want ~100 VGPR.
// ---------------------------------------------------------------------------
__global__ __launch_bounds__(256, 2) void edge_kernel(
                            const unsigned char* __restrict__ A1u,
                            const unsigned char* __restrict__ A2q,
                            const float* __restrict__ R1,
                            const float* __restrict__ R2,
                            const float* __restrict__ qs,
                            const int* __restrict__ npp,
                            const int* __restrict__ flagp,
                            const int* __restrict__ src,
                            const int* __restrict__ dst,
                            float* __restrict__ out,
                            int E, int K) {
    const int lane = threadIdx.x & 63;
    const int gw   = blockIdx.x * 4 + (threadIdx.x >> 6);
    const float k0 = qs[1];
    const int np   = *npp;
    const int flag = *flagp;

    // mask dword m=4d+k: byte b on iff rank 16d+4b+k < np  (wave-uniform)
    unsigned M[32];
    #pragma unroll
    for (int m = 0; m < 32; ++m) {
        const int d = m >> 2, k = m & 3;
        const int t = np - 16 * d - k;
        int bc = (t <= 0) ? 0 : ((t + 3) >> 2);
        bc = bc > 4 ? 4 : bc;
        M[m] = (bc >= 4) ? 0xFFFFFFFFu
             : ((bc <= 0) ? 0u : (0xFFFFFFFFu >> (8 * (4 - bc))));
    }

    const int e = gw * 64 + lane;
    if (e >= E) return;
    int dv, slot;
    if (!flag) { dv = e >> 4; slot = e & 15; }
    else {
        dv = dst[e];
        int lo = 0, hi = e;
        while (lo < hi) {
            int mid = (lo + hi) >> 1;
            if (dst[mid] < dv) lo = mid + 1; else hi = mid;
        }
        slot = e - lo;
    }
    const int se = src[e];

    const unsigned char* bp = A2q + (long)se * 32;
    int4 q0 = *(const int4*)(bp);
    int4 q1 = *(const int4*)(bp + 16);
    const unsigned char* ap_ = A1u + (long)dv * 128;
    unsigned A[32];
    #pragma unroll
    for (int i = 0; i < 8; ++i) {
        int4 t = *(const int4*)(ap_ + i * 16);
        A[4 * i]     = (unsigned)t.x;
        A[4 * i + 1] = (unsigned)t.y;
        A[4 * i + 2] = (unsigned)t.z;
        A[4 * i + 3] = (unsigned)t.w;
    }
    const float r12 = R1[dv] + R2[se];

    unsigned B[8] = {(unsigned)q0.x, (unsigned)q0.y, (unsigned)q0.z, (unsigned)q0.w,
                     (unsigned)q1.x, (unsigned)q1.y, (unsigned)q1.z, (unsigned)q1.w};
    unsigned sall = 0, spl = 0;
    #pragma unroll
    for (int d = 0; d < 8; ++d) {
        const unsigned v = B[d];
        #pragma unroll
        for (int k = 0; k < 4; ++k) {
            unsigned x = (v >> (2 * k)) & 0x03030303u;
            unsigned y = x + (x << 2);     // x*5
            y = y + (y << 4);              // x*85  (no cross-byte carries)
            const unsigned mm = M[4 * d + k];
            const unsigned aa = A[4 * d + k];
            sall = sad8(aa, y, sall);
            spl  = sad8(aa & mm, y & mm, spl);
        }
    }

    const float score = fmaf(k0, 2.0f * (float)spl - (float)sall, r12);
    if (slot < K) out[(long)dv * K + slot] = score;
    if (!flag) out[(long)dv * K + 16 + slot] = -1e10f;
}

// ---------------------------------------------------------------------------
// Fallback (round-1 kernel) for non-special shapes / tiny ws.
// ---------------------------------------------------------------------------
__global__ void attack_kernel_f(
    const float* __restrict__ nf, const float* __restrict__ b1,
    const float* __restrict__ W2, const float* __restrict__ b2,
    const int* __restrict__ src, const int* __restrict__ dst,
    const __bf16* __restrict__ W1t, float* __restrict__ out,
    int T, int K, int DEG)
{
    const int lane = threadIdx.x & 63;
    const int wid  = threadIdx.x >> 6;
    const int row  = lane & 15;
    const int kg   = lane >> 4;

    bf16x8 bfrag[8][4];
    #pragma unroll
    for (int ct = 0; ct < 8; ++ct) {
        const __bf16* colp = W1t + (ct * 16 + row) * 128 + kg * 8;
        #pragma unroll
        for (int kk = 0; kk < 4; ++kk)
            bfrag[ct][kk] = *(const bf16x8*)(colp + kk * 32);
    }
    float b1c[8], w2c[8];
    #pragma unroll
    for (int ct = 0; ct < 8; ++ct) {
        b1c[ct] = b1[ct * 16 + row];
        w2c[ct] = W2[ct * 16 + row];
    }
    const float b2v = b2[0];

    const int wstride = gridDim.x * 4;
    for (int t = blockIdx.x * 4 + wid; t < T; t += wstride) {
        const long eb = (long)t * DEG;
        const int dv = dst[eb];
        const int sv = src[eb + row];
        bf16x8 afrag[4];
        const float* dp = nf + (long)dv * 64 + kg * 8;
        const float* sp = nf + (long)sv * 64 + kg * 8;
        #pragma unroll
        for (int kk = 0; kk < 2; ++kk) {
            f32x4 lo = *(const f32x4*)(dp + kk * 32);
            f32x4 hi = *(const f32x4*)(dp + kk * 32 + 4);
            bf16x8 a;
            #pragma unroll
            for (int j = 0; j < 4; ++j) { a[j] = (__bf16)lo[j]; a[4 + j] = (__bf16)hi[j]; }
            afrag[kk] = a;
        }
        #pragma unroll
        for (int kk = 0; kk < 2; ++kk) {
            f32x4 lo = *(const f32x4*)(sp + kk * 32);
            f32x4 hi = *(const f32x4*)(sp + kk * 32 + 4);
            bf16x8 a;
            #pragma unroll
            for (int j = 0; j < 4; ++j) { a[j] = (__bf16)lo[j]; a[4 + j] = (__bf16)hi[j]; }
            afrag[2 + kk] = a;
        }
        f32x4 acc[8];
        #pragma unroll
        for (int ct = 0; ct < 8; ++ct) acc[ct] = (f32x4){0.f, 0.f, 0.f, 0.f};
        #pragma unroll
        for (int ct = 0; ct < 8; ++ct) {
            #pragma unroll
            for (int kk = 0; kk < 4; ++kk)
                acc[ct] = __builtin_amdgcn_mfma_f32_16x16x32_bf16(
                    afrag[kk], bfrag[ct][kk], acc[ct], 0, 0, 0);
        }
        float part[4] = {0.f, 0.f, 0.f, 0.f};
        #pragma unroll
        for (int ct = 0; ct < 8; ++ct) {
            #pragma unroll
            for (int r = 0; r < 4; ++r) {
                float h = acc[ct][r] + b1c[ct];
                h = fmaxf(h, 0.01f * h);
                part[r] = fmaf(h, w2c[ct], part[r]);
            }
        }
        #pragma unroll
        for (int m = 1; m < 16; m <<= 1) {
            #pragma unroll
            for (int r = 0; r < 4; ++r)
                part[r] += __shfl_xor(part[r], m, 64);
        }
        float* orow = out + (long)dv * K;
        if (row == 0) {
            f32x4 v;
            #pragma unroll
            for (int r = 0; r < 4; ++r) v[r] = part[r] + b2v;
            *(f32x4*)(orow + kg * 4) = v;
            *(f32x4*)(orow + DEG + kg * 4) = (f32x4){-1e10f, -1e10f, -1e10f, -1e10f};
        }
    }
}

extern "C" void kernel_launch(void* const* d_in, const int* in_sizes, int n_in,
                              void* d_out, int out_size, void* d_ws, size_t ws_size,
                              hipStream_t stream) {
    const float* nf  = (const float*)d_in[0];
    const float* W1  = (const float*)d_in[1];
    const float* b1  = (const float*)d_in[2];
    const float* W2  = (const float*)d_in[3];
    const float* b2  = (const float*)d_in[4];
    const int*   src = (const int*)d_in[5];
    const int*   dst = (const int*)d_in[6];
    float* out = (float*)d_out;

    const int H    = in_sizes[2];          // 128
    const int twoD = in_sizes[1] / H;      // 128
    const int D    = twoD / 2;             // 64
    const int N    = in_sizes[0] / D;      // 100000
    const int E    = in_sizes[5];          // 1600000
    const int DEG  = E / N;                // 16
    const int K    = out_size / N;         // 32

    // ws layout
    const size_t w1_off   = 0;                 // 32 KiB (W1pt or W1t)
    const size_t qs_off   = 32768;             // 16 B
    const size_t np_off   = 32784;             // 4 B
    const size_t flag_off = 32788;             // 4 B
    const size_t b1p_off  = 33312;             // 512 B
    const size_t w2p_off  = 33824;             // 512 B
    const size_t A1_off   = 34560;             // 256-aligned
    const size_t A1_sz    = (size_t)N * 128;   // u8 table (12.8 MB)
    const size_t A2_off   = A1_off + A1_sz;
    const size_t A2_sz    = (size_t)N * 32;    // 2-bit table (3.2 MB)
    const size_t R1_off   = A2_off + A2_sz;
    const size_t R2_off   = R1_off + (size_t)N * sizeof(float);
    const size_t need     = R2_off + (size_t)N * sizeof(float);

    const bool special = (D == 64 && H == 128 && DEG == 16 && K == 32 &&
                          (N % 16) == 0 && (E % 64) == 0 && ws_size >= need);
    if (special) {
        __bf16*        W1pt = (__bf16*)((char*)d_ws + w1_off);
        float*         qs   = (float*)((char*)d_ws + qs_off);
        int*           npp  = (int*)((char*)d_ws + np_off);
        int*           flg  = (int*)((char*)d_ws + flag_off);
        float*         b1p  = (float*)((char*)d_ws + b1p_off);
        float*         w2p  = (float*)((char*)d_ws + w2p_off);
        unsigned char* A1u  = (unsigned char*)d_ws + A1_off;
        unsigned char* A2q  = (unsigned char*)d_ws + A2_off;
        float*         R1   = (float*)((char*)d_ws + R1_off);
        float*         R2   = (float*)((char*)d_ws + R2_off);

        prep_kernel<<<64, 256, 0, stream>>>(W1, b1, W2, W1pt, b1p, w2p,
                                            npp, qs, flg);
        verify_dst_kernel<<<(E / 4 + 255) / 256, 256, 0, stream>>>(dst, E, flg);
        const int T2 = N / 16;
        const int pblocks = (T2 + 3) / 4;          // 1 tile per wave
        precomp_kernel<<<pblocks, 256, 0, stream>>>(nf, b1p, w2p, b2, W1pt, qs,
                                                    flg, A1u, A2q, R1, R2,
                                                    out, T2, K);
        const int eblocks = (E + 255) / 256;       // 64 edges per wave, one-shot
        edge_kernel<<<eblocks, 256, 0, stream>>>(A1u, A2q, R1, R2, qs, npp,
                                                 flg, src, dst, out, E, K);
    } else {
        __bf16* W1t = (__bf16*)((char*)d_ws + w1_off);
        prep_w1_kernel<<<(twoD * H + 255) / 256, 256, 0, stream>>>(W1, W1t);
        attack_kernel_f<<<2048, 256, 0, stream>>>(nf, b1, W2, b2, src, dst,
                                                  W1t, out, N, K, DEG);
    }
}